// Round 1
// baseline (292.842 us; speedup 1.0000x reference)
//
#include <hip/hip_runtime.h>
#include <hip/hip_bf16.h>

// Problem geometry (fixed by the reference):
//   x: (B=16, C=64, S=512, S=512) fp32
//   out: (16, 64, 256, 256) fp32
//   out[b,c,ho,wo] = w[c] * mean(x[b,c,2ho:2ho+2,2wo:2wo+2]) + bias[c]

#define B_ 16
#define C_ 64
#define S_ 512
#define HO (S_ / 2)   // 256
#define WO (S_ / 2)   // 256

// Each work-unit = 2 adjacent output pixels (one float2 store, two float4 loads).
// Units per output row: WO/2 = 128.
#define UNITS_PER_ROW (WO / 2)                     // 128
#define UNITS_PER_CH  (UNITS_PER_ROW * HO)         // 32768
#define UNITS_PER_IMG (UNITS_PER_CH * C_)          // 2097152
#define TOTAL_UNITS   (UNITS_PER_IMG * B_)         // 33554432

__global__ __launch_bounds__(256) void avgpool_affine_kernel(
    const float* __restrict__ x,
    const float* __restrict__ weight,
    const float* __restrict__ bias,
    float* __restrict__ out)
{
    const long long stride = (long long)gridDim.x * blockDim.x;
    for (long long i = (long long)blockIdx.x * blockDim.x + threadIdx.x;
         i < (long long)TOTAL_UNITS; i += stride)
    {
        // Decompose unit index
        const int u    = (int)i;
        const int wu   = u & (UNITS_PER_ROW - 1);          // 0..127
        const int ho   = (u >> 7) & (HO - 1);              // 0..255
        const int bc   = u >> 15;                          // b*C + c, 0..1023
        const int c    = bc & (C_ - 1);

        // Input base: row 2*ho, col 4*wu of channel plane (b,c)
        const long long plane = (long long)bc * (S_ * S_);
        const long long base  = plane + (long long)(2 * ho) * S_ + 4 * wu;

        const float4 r0 = *reinterpret_cast<const float4*>(x + base);
        const float4 r1 = *reinterpret_cast<const float4*>(x + base + S_);

        const float w = weight[c];
        const float bs = bias[c];

        float2 o;
        o.x = w * (0.25f * (r0.x + r0.y + r1.x + r1.y)) + bs;
        o.y = w * (0.25f * (r0.z + r0.w + r1.z + r1.w)) + bs;

        // Output: same (b,c,ho), cols 2*wu, 2*wu+1
        const long long obase = (long long)bc * (HO * WO) + (long long)ho * WO + 2 * wu;
        *reinterpret_cast<float2*>(out + obase) = o;
    }
}

extern "C" void kernel_launch(void* const* d_in, const int* in_sizes, int n_in,
                              void* d_out, int out_size, void* d_ws, size_t ws_size,
                              hipStream_t stream)
{
    const float* x      = (const float*)d_in[0];
    const float* weight = (const float*)d_in[1];
    const float* bias   = (const float*)d_in[2];
    float* out          = (float*)d_out;

    const int block = 256;
    const int grid  = 2048;   // 256 CUs * 8 blocks/CU; grid-stride covers the rest
    avgpool_affine_kernel<<<grid, block, 0, stream>>>(x, weight, bias, out);
}

// Round 2
// 240.837 us; speedup vs baseline: 1.2159x; 1.2159x over previous
//
#include <hip/hip_runtime.h>
#include <hip/hip_bf16.h>

// Problem geometry (fixed by the reference):
//   x: (B=16, C=64, S=512, S=512) fp32
//   out: (16, 64, 256, 256) fp32
//   out[b,c,ho,wo] = w[c] * mean(x[b,c,2ho:2ho+2,2wo:2wo+2]) + bias[c]

#define B_ 16
#define C_ 64
#define S_ 512
#define HO (S_ / 2)   // 256
#define WO (S_ / 2)   // 256

// One wave (64 lanes) produces one full output row (256 floats, float4/lane).
// Lane i reads input cols [8i, 8i+8) of rows {2ho, 2ho+1}: 4x float4 loads.
// The wave's combined read footprint is one contiguous 4 KiB block.
#define ROWS_TOTAL (B_ * C_ * HO)   // 262144 output rows

typedef float f32x4 __attribute__((ext_vector_type(4)));

__global__ __launch_bounds__(256) void avgpool_affine_kernel(
    const float* __restrict__ x,
    const float* __restrict__ weight,
    const float* __restrict__ bias,
    float* __restrict__ out)
{
    const int lane       = threadIdx.x & 63;
    const int wave       = (blockIdx.x * blockDim.x + threadIdx.x) >> 6;
    const int numWaves   = (gridDim.x * blockDim.x) >> 6;

    for (int row = wave; row < ROWS_TOTAL; row += numWaves)
    {
        const int ho = row & (HO - 1);        // 0..255
        const int bc = row >> 8;              // b*C + c
        const int c  = bc & (C_ - 1);

        const long long ibase = (long long)bc * (S_ * S_)
                              + (long long)(2 * ho) * S_ + 8 * lane;

        const f32x4 a0 = __builtin_nontemporal_load(
            reinterpret_cast<const f32x4*>(x + ibase));
        const f32x4 a1 = __builtin_nontemporal_load(
            reinterpret_cast<const f32x4*>(x + ibase + 4));
        const f32x4 b0 = __builtin_nontemporal_load(
            reinterpret_cast<const f32x4*>(x + ibase + S_));
        const f32x4 b1 = __builtin_nontemporal_load(
            reinterpret_cast<const f32x4*>(x + ibase + S_ + 4));

        const float w  = weight[c];
        const float bs = bias[c];

        f32x4 o;
        o.x = __builtin_fmaf(w, 0.25f * (a0.x + a0.y + b0.x + b0.y), bs);
        o.y = __builtin_fmaf(w, 0.25f * (a0.z + a0.w + b0.z + b0.w), bs);
        o.z = __builtin_fmaf(w, 0.25f * (a1.x + a1.y + b1.x + b1.y), bs);
        o.w = __builtin_fmaf(w, 0.25f * (a1.z + a1.w + b1.z + b1.w), bs);

        const long long obase = (long long)bc * (HO * WO)
                              + (long long)ho * WO + 4 * lane;
        __builtin_nontemporal_store(o, reinterpret_cast<f32x4*>(out + obase));
    }
}

extern "C" void kernel_launch(void* const* d_in, const int* in_sizes, int n_in,
                              void* d_out, int out_size, void* d_ws, size_t ws_size,
                              hipStream_t stream)
{
    const float* x      = (const float*)d_in[0];
    const float* weight = (const float*)d_in[1];
    const float* bias   = (const float*)d_in[2];
    float* out          = (float*)d_out;

    const int block = 256;   // 4 waves/block
    const int grid  = 2048;  // 8192 waves; 32 rows per wave, grid-stride
    avgpool_affine_kernel<<<grid, block, 0, stream>>>(x, weight, bias, out);
}

// Round 4
// 234.058 us; speedup vs baseline: 1.2512x; 1.0290x over previous
//
#include <hip/hip_runtime.h>
#include <hip/hip_bf16.h>

// Problem geometry (fixed by the reference):
//   x: (B=16, C=64, S=512, S=512) fp32
//   out: (16, 64, 256, 256) fp32
//   out[b,c,ho,wo] = w[c] * mean(x[b,c,2ho:2ho+2,2wo:2wo+2]) + bias[c]

#define B_ 16
#define C_ 64
#define S_ 512
#define HO (S_ / 2)   // 256
#define WO (S_ / 2)   // 256

// One wave iteration = 2 consecutive output rows (one "row-pair" unit):
//   reads input rows [4u, 4u+4) of a channel plane — contiguous 8 KiB/wave
//   writes output rows [2u, 2u+2)                 — contiguous 2 KiB/wave
// Lane i handles input cols [8i, 8i+8) (two float4 per row).
#define PAIRS_PER_CH  (HO / 2)                    // 128
#define PAIRS_TOTAL   (B_ * C_ * PAIRS_PER_CH)    // 131072

typedef float f32x4 __attribute__((ext_vector_type(4)));

__global__ __launch_bounds__(256) void avgpool_affine_kernel(
    const float* __restrict__ x,
    const float* __restrict__ weight,
    const float* __restrict__ bias,
    float* __restrict__ out)
{
    const int lane     = threadIdx.x & 63;
    const int wave     = (blockIdx.x * blockDim.x + threadIdx.x) >> 6;
    const int numWaves = (gridDim.x * blockDim.x) >> 6;

    for (int u = wave; u < PAIRS_TOTAL; u += numWaves)
    {
        const int p  = u & (PAIRS_PER_CH - 1);    // 0..127
        const int bc = u >> 7;                    // b*C + c
        const int c  = bc & (C_ - 1);

        const long long ibase = (long long)bc * (S_ * S_)
                              + (long long)(4 * p) * S_ + 8 * lane;

        // rows 4p, 4p+1 -> output row 2p
        const f32x4 a0 = __builtin_nontemporal_load(reinterpret_cast<const f32x4*>(x + ibase));
        const f32x4 a1 = __builtin_nontemporal_load(reinterpret_cast<const f32x4*>(x + ibase + 4));
        const f32x4 b0 = __builtin_nontemporal_load(reinterpret_cast<const f32x4*>(x + ibase + S_));
        const f32x4 b1 = __builtin_nontemporal_load(reinterpret_cast<const f32x4*>(x + ibase + S_ + 4));
        // rows 4p+2, 4p+3 -> output row 2p+1
        const f32x4 c0 = __builtin_nontemporal_load(reinterpret_cast<const f32x4*>(x + ibase + 2 * S_));
        const f32x4 c1 = __builtin_nontemporal_load(reinterpret_cast<const f32x4*>(x + ibase + 2 * S_ + 4));
        const f32x4 d0 = __builtin_nontemporal_load(reinterpret_cast<const f32x4*>(x + ibase + 3 * S_));
        const f32x4 d1 = __builtin_nontemporal_load(reinterpret_cast<const f32x4*>(x + ibase + 3 * S_ + 4));

        const float w  = weight[c];
        const float bs = bias[c];

        f32x4 o0, o1;
        o0.x = __builtin_fmaf(w, 0.25f * (a0.x + a0.y + b0.x + b0.y), bs);
        o0.y = __builtin_fmaf(w, 0.25f * (a0.z + a0.w + b0.z + b0.w), bs);
        o0.z = __builtin_fmaf(w, 0.25f * (a1.x + a1.y + b1.x + b1.y), bs);
        o0.w = __builtin_fmaf(w, 0.25f * (a1.z + a1.w + b1.z + b1.w), bs);
        o1.x = __builtin_fmaf(w, 0.25f * (c0.x + c0.y + d0.x + d0.y), bs);
        o1.y = __builtin_fmaf(w, 0.25f * (c0.z + c0.w + d0.z + d0.w), bs);
        o1.z = __builtin_fmaf(w, 0.25f * (c1.x + c1.y + d1.x + d1.y), bs);
        o1.w = __builtin_fmaf(w, 0.25f * (c1.z + c1.w + d1.z + d1.w), bs);

        const long long obase = (long long)bc * (HO * WO)
                              + (long long)(2 * p) * WO + 4 * lane;
        __builtin_nontemporal_store(o0, reinterpret_cast<f32x4*>(out + obase));
        __builtin_nontemporal_store(o1, reinterpret_cast<f32x4*>(out + obase + WO));
    }
}

extern "C" void kernel_launch(void* const* d_in, const int* in_sizes, int n_in,
                              void* d_out, int out_size, void* d_ws, size_t ws_size,
                              hipStream_t stream)
{
    const float* x      = (const float*)d_in[0];
    const float* weight = (const float*)d_in[1];
    const float* bias   = (const float*)d_in[2];
    float* out          = (float*)d_out;

    const int block = 256;   // 4 waves/block
    const int grid  = 2048;  // 8192 waves; 16 row-pair units per wave
    avgpool_affine_kernel<<<grid, block, 0, stream>>>(x, weight, bias, out);
}